// Round 2
// baseline (264.919 us; speedup 1.0000x reference)
//
#include <hip/hip_runtime.h>
#include <cstddef>

#define BB 32
#define NN 256
#define RR 5

typedef __attribute__((ext_vector_type(8))) short bf16x8;
typedef __attribute__((ext_vector_type(4))) float f32x4;

__device__ __forceinline__ float lrelu(float x) { return x >= 0.f ? x : 0.2f * x; }
// RNE float -> bf16
__device__ __forceinline__ unsigned short f2bf(float x) {
    unsigned u = __float_as_uint(x);
    u += 0x7FFFu + ((u >> 16) & 1u);
    return (unsigned short)(u >> 16);
}
__device__ __forceinline__ float bf2f(unsigned short u) {
    return __uint_as_float((unsigned)u << 16);
}

// =======================================================================================
// k_prep: blocks 0..29: W (K x 640 fp32) -> WT (640 x K bf16).
// blocks 30..2077: pack y_bonds -> maskp, 4 items/thread via int4 loads + uint store.
// =======================================================================================
__global__ __launch_bounds__(256) void k_prep(const float* __restrict__ W1,
                                              const float* __restrict__ W2,
                                              const float* __restrict__ W3,
                                              const int* __restrict__ bonds,
                                              unsigned short* __restrict__ WT1,
                                              unsigned short* __restrict__ WT2,
                                              unsigned short* __restrict__ WT3,
                                              unsigned char* __restrict__ maskp) {
    int blk = blockIdx.x;
    int t = threadIdx.x;
    if (blk < 30) {
        int layer = blk / 10, nt = blk % 10;
        const float* W;
        unsigned short* WT;
        int K;
        if (layer == 0)      { W = W1; WT = WT1; K = 64; }
        else if (layer == 1) { W = W2; WT = WT2; K = 128; }
        else                 { W = W3; WT = WT3; K = 128; }
        int n = nt * 64 + (t & 63);
        for (int kg = (int)(t >> 6); kg < K / 8; kg += 4) {
            bf16x8 v;
#pragma unroll
            for (int e = 0; e < 8; ++e) v[e] = (short)f2bf(W[(size_t)(kg * 8 + e) * 640 + n]);
            *(bf16x8*)&WT[(size_t)n * K + kg * 8] = v;
        }
    } else {
        int gt = (blk - 30) * 256 + t;                 // 524288 threads, 4 items each
        const int4* p = (const int4*)(bonds + (size_t)gt * 20);
        int4 q0 = p[0], q1 = p[1], q2 = p[2], q3 = p[3], q4 = p[4];
        int v[20] = {q0.x, q0.y, q0.z, q0.w, q1.x, q1.y, q1.z, q1.w,
                     q2.x, q2.y, q2.z, q2.w, q3.x, q3.y, q3.z, q3.w,
                     q4.x, q4.y, q4.z, q4.w};
        unsigned m = 0;
#pragma unroll
        for (int k = 0; k < 4; ++k)
#pragma unroll
            for (int r = 0; r < 5; ++r)
                m |= (v[k * 5 + r] == 1) ? (1u << (k * 8 + r)) : 0u;
        *(unsigned*)&maskp[(size_t)gt * 4] = m;
    }
}

// =======================================================================================
// gemm_h: h = A(8192 x K) @ W(K x 640) + bias, MFMA bf16 (fp32 accum).
// MODE 0: A = fp32 Af32 (layer 1). MODE 1: A = final bf16 Ab written by k_agg (plain load).
// Emits src/dst partial dots (2 halves) and hTf fragment-native:
//   hTf[((b*5 + r)*32 + joct)*1024 + c*8 + e]   (joct = j/8, e = j%8)
// grid (10 n-tiles of 64, 128 m-tiles of 64), 256 threads = 4 waves.
// =======================================================================================
template <int K, int MODE>
__global__ __launch_bounds__(256) void k_gemm_h(const float* __restrict__ Af32,
                                                const unsigned short* __restrict__ Ab,
                                                const unsigned short* __restrict__ WTg,
                                                const float* __restrict__ bias,
                                                const float* __restrict__ avec,
                                                float* __restrict__ srcp,
                                                float* __restrict__ dstp,
                                                unsigned short* __restrict__ hTf) {
    const int t = threadIdx.x;
    const int n0 = blockIdx.x * 64, m0 = blockIdx.y * 64;
    const int w = t >> 6, lane = t & 63;
    const int colg = lane & 15, rquad = lane >> 4;
    const int m = m0 + w * 16 + colg;        // A row this lane reads
    const int koff = rquad * 8;

    f32x4 acc[4] = {};
#pragma unroll
    for (int kk = 0; kk < K; kk += 32) {
        bf16x8 af;
        size_t off = (size_t)m * K + kk + koff;
        if (MODE == 1) {
            af = *(const bf16x8*)&Ab[off];
        } else {
            float4 q0 = *(const float4*)&Af32[off];
            float4 q1 = *(const float4*)&Af32[off + 4];
            af[0] = (short)f2bf(q0.x); af[1] = (short)f2bf(q0.y);
            af[2] = (short)f2bf(q0.z); af[3] = (short)f2bf(q0.w);
            af[4] = (short)f2bf(q1.x); af[5] = (short)f2bf(q1.y);
            af[6] = (short)f2bf(q1.z); af[7] = (short)f2bf(q1.w);
        }
#pragma unroll
        for (int ct = 0; ct < 4; ++ct) {
            bf16x8 bfv = *(const bf16x8*)&WTg[(size_t)(n0 + ct * 16 + colg) * K + kk + koff];
            acc[ct] = __builtin_amdgcn_mfma_f32_16x16x32_bf16(af, bfv, acc[ct], 0, 0, 0);
        }
    }

    // ---- epilogue: bias, src/dst partial dots (shfl-reduce over colg), hTf stores ----
    const int r = n0 >> 7, chalf = n0 & 127;
    const int b = m0 >> 8, jb = m0 & 255;
    float val[4][4];
    float ssum[4] = {0.f, 0.f, 0.f, 0.f}, dsum[4] = {0.f, 0.f, 0.f, 0.f};
#pragma unroll
    for (int ct = 0; ct < 4; ++ct) {
        int cg = chalf + ct * 16 + colg;
        float bv = bias[n0 + ct * 16 + colg];
        float asr = avec[r * 256 + cg];
        float ads = avec[r * 256 + 128 + cg];
#pragma unroll
        for (int reg = 0; reg < 4; ++reg) {
            float v = acc[ct][reg] + bv;
            val[ct][reg] = v;
            ssum[reg] += v * asr;
            dsum[reg] += v * ads;
        }
    }
#pragma unroll
    for (int mk = 1; mk < 16; mk <<= 1)
#pragma unroll
        for (int reg = 0; reg < 4; ++reg) {
            ssum[reg] += __shfl_xor(ssum[reg], mk);
            dsum[reg] += __shfl_xor(dsum[reg], mk);
        }
    if (colg == 0) {
        int half = (n0 >> 6) & 1;
#pragma unroll
        for (int reg = 0; reg < 4; ++reg) {
            int row = m0 + w * 16 + rquad * 4 + reg;
            srcp[half * 40960 + row * 5 + r] = ssum[reg];
            dstp[half * 40960 + row * 5 + r] = dsum[reg];
        }
    }
    // hTf direct stores: reg-quad = 4 consecutive j (8 B contiguous)
    {
        const int joct = (jb >> 3) + w * 2 + (rquad >> 1);
        const size_t tile = (size_t)((b * 5 + r) * 32 + joct) * 1024;
        const int sub = (rquad & 1) * 4;
#pragma unroll
        for (int ct = 0; ct < 4; ++ct) {
            int c = chalf + ct * 16 + colg;
            uint2 pk;
            pk.x = (unsigned)f2bf(val[ct][0]) | ((unsigned)f2bf(val[ct][1]) << 16);
            pk.y = (unsigned)f2bf(val[ct][2]) | ((unsigned)f2bf(val[ct][3]) << 16);
            *(uint2*)&hTf[tile + (size_t)c * 8 + sub] = pk;
        }
    }
}

// =======================================================================================
// k_agg: grid (16 i-tiles of 16, 32 b) = 512 blocks, 512 threads = 8 waves.
// Full j-range (256) per block: computes the complete softmax row sum Z, so it writes the
// FINAL normalized output directly:
//   FINAL=0: Ab[row][c] = bf16(lrelu(agg/Z))  (layers 1-2 -> next gemm A operand)
//   FINAL=1: Ab32[row][c] = fp32(agg/Z)       (layer 3 -> pooling)
// LDS: Ps 40 KB + Ds2l 5 KB + misc ~= 46 KB -> 2 blocks/CU (grid exactly 2/CU).
// =======================================================================================
template <int FINAL>
__global__ __launch_bounds__(512, 4) void k_agg(const unsigned short* __restrict__ hTf,
                                                const float* __restrict__ srcp,
                                                const float* __restrict__ dstp,
                                                const unsigned char* __restrict__ maskp,
                                                unsigned short* __restrict__ Ab,
                                                float* __restrict__ Ab32) {
    __shared__ __align__(16) unsigned short Ps[20480];   // 16 i x 1280 k bf16 = 40 KB
    __shared__ __align__(16) float Ds2l[1280];
    __shared__ float Ss[80], Zw[128], Zrow[16];
    const int t = threadIdx.x;
    const int itile = blockIdx.x, b = blockIdx.y;
    const int ib = b * 256 + itile * 16;
    const int w = t >> 6, lane = t & 63;
    const int colg = lane & 15, rquad = lane >> 4;
    const int c = w * 16 + colg;                          // output column this wave owns
    const size_t bbase = (size_t)(b * 5) * 32 * 1024;

    if (t < 80) Ss[t] = srcp[(size_t)ib * 5 + t] + srcp[40960 + (size_t)ib * 5 + t];
    for (int idx = t; idx < 1280; idx += 512) {
        int jl = idx & 255, rr = idx >> 8;
        size_t o = (size_t)(b * 256 + jl) * 5 + rr;
        Ds2l[rr * 256 + jl] = dstp[o] + dstp[40960 + o];
    }
    // B prefetch for MFMA steps 0..3 (independent of Ps; streams under P-gen VALU)
    bf16x8 pre[4];
#pragma unroll
    for (int s = 0; s < 4; ++s)
        pre[s] = *(const bf16x8*)&hTf[bbase + (size_t)(s * 4 + rquad) * 1024 + (size_t)c * 8];
    __syncthreads();

    // P generation: 2560 chunks of 8; thread t -> chunks it*512+t (i = t&15 fixed)
    {
        const int i = t & 15;
        const int kq = (t >> 4) & 3;
        float esum = 0.f;
#pragma unroll
        for (int it = 0; it < 5; ++it) {
            int p = it * 512 + t;
            int s = p >> 6;                           // s in [0,40)
            int k0 = s * 32 + kq * 8;                 // k0 in [0,1280)
            int rr = k0 >> 8, j0 = k0 & 255;
            uint2 mk8 = *(const uint2*)&maskp[((size_t)(ib + i) << 8) + j0];
            float sv = Ss[i * 5 + rr];
            float4 d0 = *(const float4*)&Ds2l[rr * 256 + j0];
            float4 d1 = *(const float4*)&Ds2l[rr * 256 + j0 + 4];
            float dv[8] = {d0.x, d0.y, d0.z, d0.w, d1.x, d1.y, d1.z, d1.w};
            bf16x8 pv;
#pragma unroll
            for (int e = 0; e < 8; ++e) {
                unsigned mb = ((e < 4 ? (mk8.x >> (8 * e)) : (mk8.y >> (8 * (e - 4)))) >> rr) & 1u;
                float vv = lrelu(sv + dv[e]);
                float ev = mb ? __expf(vv) : 0.f;
                unsigned short q = f2bf(ev);
                pv[e] = (short)q;
                esum += __uint_as_float((unsigned)q << 16);
            }
            *(bf16x8*)&Ps[p * 8] = pv;
        }
        // lanes {i, i+16, i+32, i+48} share i -> butterfly over bits 4,5
        esum += __shfl_xor(esum, 16);
        esum += __shfl_xor(esum, 32);
        if (lane < 16) Zw[w * 16 + (lane & 15)] = esum;
    }
    __syncthreads();
    if (t < 16) {
        float z = 0.f;
#pragma unroll
        for (int ww = 0; ww < 8; ++ww) z += Zw[ww * 16 + t];
        Zrow[t] = 1.f / z;                            // store reciprocal once
    }

    // MFMA: wave w -> 16 columns; 40 steps over (r, j-window); 2 accumulator chains
    f32x4 acc0 = {}, acc1 = {};
#pragma unroll
    for (int s = 0; s < 8; ++s) {                     // peeled: static pre[] indexing
        bf16x8 af = *(const bf16x8*)&Ps[(s * 64 + lane) * 8];
        bf16x8 bfv;
        if (s < 4) bfv = pre[s];
        else bfv = *(const bf16x8*)&hTf[bbase + (size_t)((s & 7) * 4 + rquad) * 1024 + (size_t)c * 8];
        if (s & 1) acc1 = __builtin_amdgcn_mfma_f32_16x16x32_bf16(af, bfv, acc1, 0, 0, 0);
        else       acc0 = __builtin_amdgcn_mfma_f32_16x16x32_bf16(af, bfv, acc0, 0, 0, 0);
    }
#pragma unroll 8
    for (int s = 8; s < 40; ++s) {
        bf16x8 af = *(const bf16x8*)&Ps[(s * 64 + lane) * 8];
        bf16x8 bfv = *(const bf16x8*)&hTf[bbase +
            (size_t)((s >> 3) * 32 + (s & 7) * 4 + rquad) * 1024 + (size_t)c * 8];
        if (s & 1) acc1 = __builtin_amdgcn_mfma_f32_16x16x32_bf16(af, bfv, acc1, 0, 0, 0);
        else       acc0 = __builtin_amdgcn_mfma_f32_16x16x32_bf16(af, bfv, acc0, 0, 0, 0);
    }
    __syncthreads();                                  // Zrow visible to all
    const int irow = ib + rquad * 4;
#pragma unroll
    for (int reg = 0; reg < 4; ++reg) {
        float v = (acc0[reg] + acc1[reg]) * Zrow[rquad * 4 + reg];
        if (FINAL) Ab32[(size_t)(irow + reg) * 128 + c] = v;
        else       Ab[(size_t)(irow + reg) * 128 + c] = f2bf(lrelu(v));
    }
}

// =======================================================================================
// k_tail: fused pool + MLP head. grid (32 b), 256 threads.
// Pool mean/max of h3 (fp32) over n; z = [x | mean | max]; mlp1 (We1 native layout,
// thread-per-output, coalesced); mlp2; mlp3.
// =======================================================================================
__global__ __launch_bounds__(256) void k_tail(const float* __restrict__ h3,
                                              const float* __restrict__ x,
                                              const float* __restrict__ We1,
                                              const float* __restrict__ be1,
                                              const float* __restrict__ We2,
                                              const float* __restrict__ be2,
                                              const float* __restrict__ We3,
                                              const float* __restrict__ be3,
                                              float* __restrict__ out) {
    __shared__ float zs[1280];
    __shared__ float Sh[2][128], Mh[2][128];
    __shared__ float z1s[256], z2s[32];
    const int b = blockIdx.x, t = threadIdx.x;
    const int cc = t & 127, sub = t >> 7;
    float sm = 0.f, mx = -3.4e38f;
    for (int nn = 0; nn < 128; ++nn) {
        float v = h3[(size_t)(b * 256 + sub * 128 + nn) * 128 + cc];
        sm += v;
        mx = fmaxf(mx, v);
    }
    Sh[sub][cc] = sm;
    Mh[sub][cc] = mx;
    for (int i = t; i < 1024; i += 256) zs[i] = x[(size_t)b * 1024 + i];
    __syncthreads();
    if (t < 128) zs[1024 + t] = (Sh[0][t] + Sh[1][t]) * (1.f / 256.f);
    else {
        int f = t - 128;
        zs[1152 + f] = fmaxf(Mh[0][f], Mh[1][f]);
    }
    __syncthreads();
    {
        float s = 0.f;
#pragma unroll 8
        for (int k = 0; k < 1280; ++k) s += zs[k] * We1[(size_t)k * 256 + t];
        z1s[t] = lrelu(s + be1[t]);
    }
    __syncthreads();
    if (t < 32) {
        float s2 = 0.f;
        for (int k = 0; k < 256; ++k) s2 += z1s[k] * We2[k * 32 + t];
        z2s[t] = lrelu(s2 + be2[t]);
    }
    __syncthreads();
    if (t == 0) {
        float s3 = 0.f;
#pragma unroll
        for (int k = 0; k < 32; ++k) s3 += z2s[k] * We3[k];
        out[b] = s3 + be3[0];
    }
}

// ---------------- workspace layout ----------------
constexpr size_t O_MASK = 0;                           // 2,097,152
constexpr size_t O_SRCP = 2097152;                     // 2 x 40960 floats
constexpr size_t O_DSTP = O_SRCP + 2ull * 40960 * 4;
constexpr size_t O_AB   = O_DSTP + 2ull * 40960 * 4;   // 8192 x 128 bf16 = 2 MB
constexpr size_t O_AB32 = O_AB + 2097152;              // 8192 x 128 fp32 = 4 MB
constexpr size_t O_HT   = O_AB32 + 4194304;            // 10.5 MB
constexpr size_t O_WT1  = O_HT + 5242880ull * 2;
constexpr size_t O_WT2  = O_WT1 + 640ull * 64 * 2;
constexpr size_t O_WT3  = O_WT2 + 640ull * 128 * 2;

extern "C" void kernel_launch(void* const* d_in, const int* in_sizes, int n_in,
                              void* d_out, int out_size, void* d_ws, size_t ws_size,
                              hipStream_t stream) {
    const float* x       = (const float*)d_in[0];
    const float* y_atoms = (const float*)d_in[1];
    const int*   y_bonds = (const int*)d_in[2];
    const float* W1 = (const float*)d_in[3];
    const float* b1 = (const float*)d_in[4];
    const float* a1 = (const float*)d_in[5];
    const float* W2 = (const float*)d_in[6];
    const float* b2 = (const float*)d_in[7];
    const float* a2 = (const float*)d_in[8];
    const float* W3 = (const float*)d_in[9];
    const float* b3 = (const float*)d_in[10];
    const float* a3 = (const float*)d_in[11];
    const float* We1 = (const float*)d_in[12];
    const float* be1 = (const float*)d_in[13];
    const float* We2 = (const float*)d_in[14];
    const float* be2 = (const float*)d_in[15];
    const float* We3 = (const float*)d_in[16];
    const float* be3 = (const float*)d_in[17];
    float* out = (float*)d_out;

    char* ws = (char*)d_ws;
    unsigned char* maskp = (unsigned char*)(ws + O_MASK);
    float* srcp = (float*)(ws + O_SRCP);
    float* dstp = (float*)(ws + O_DSTP);
    unsigned short* Ab = (unsigned short*)(ws + O_AB);
    float* Ab32 = (float*)(ws + O_AB32);
    unsigned short* hTf = (unsigned short*)(ws + O_HT);
    unsigned short* WT1 = (unsigned short*)(ws + O_WT1);
    unsigned short* WT2 = (unsigned short*)(ws + O_WT2);
    unsigned short* WT3 = (unsigned short*)(ws + O_WT3);

    dim3 blk(256);

    k_prep<<<2078, blk, 0, stream>>>(W1, W2, W3, y_bonds, WT1, WT2, WT3, maskp);

    // layer 1
    k_gemm_h<64, 0><<<dim3(10, 128), blk, 0, stream>>>(
        y_atoms, nullptr, WT1, b1, a1, srcp, dstp, hTf);
    k_agg<0><<<dim3(16, 32), dim3(512), 0, stream>>>(hTf, srcp, dstp, maskp, Ab, nullptr);

    // layer 2
    k_gemm_h<128, 1><<<dim3(10, 128), blk, 0, stream>>>(
        nullptr, Ab, WT2, b2, a2, srcp, dstp, hTf);
    k_agg<0><<<dim3(16, 32), dim3(512), 0, stream>>>(hTf, srcp, dstp, maskp, Ab, nullptr);

    // layer 3
    k_gemm_h<128, 1><<<dim3(10, 128), blk, 0, stream>>>(
        nullptr, Ab, WT3, b3, a3, srcp, dstp, hTf);
    k_agg<1><<<dim3(16, 32), dim3(512), 0, stream>>>(hTf, srcp, dstp, maskp, nullptr, Ab32);

    // fused pool + MLP head
    k_tail<<<32, blk, 0, stream>>>(Ab32, x, We1, be1, We2, be2, We3, be3, out);
}

// Round 3
// 221.601 us; speedup vs baseline: 1.1955x; 1.1955x over previous
//
#include <hip/hip_runtime.h>
#include <cstddef>

#define BB 32
#define NN 256
#define RR 5

typedef __attribute__((ext_vector_type(8))) short bf16x8;
typedef __attribute__((ext_vector_type(4))) float f32x4;

__device__ __forceinline__ float lrelu(float x) { return x >= 0.f ? x : 0.2f * x; }
// RNE float -> bf16
__device__ __forceinline__ unsigned short f2bf(float x) {
    unsigned u = __float_as_uint(x);
    u += 0x7FFFu + ((u >> 16) & 1u);
    return (unsigned short)(u >> 16);
}
__device__ __forceinline__ float bf2f(unsigned short u) {
    return __uint_as_float((unsigned)u << 16);
}

// =======================================================================================
// k_prep: blocks 0..29: W (K x 640 fp32) -> WT (640 x K bf16).
// blocks 30..2077: pack y_bonds -> maskp, 4 items/thread via int4 loads + uint store.
// =======================================================================================
__global__ __launch_bounds__(256) void k_prep(const float* __restrict__ W1,
                                              const float* __restrict__ W2,
                                              const float* __restrict__ W3,
                                              const int* __restrict__ bonds,
                                              unsigned short* __restrict__ WT1,
                                              unsigned short* __restrict__ WT2,
                                              unsigned short* __restrict__ WT3,
                                              unsigned char* __restrict__ maskp) {
    int blk = blockIdx.x;
    int t = threadIdx.x;
    if (blk < 30) {
        int layer = blk / 10, nt = blk % 10;
        const float* W;
        unsigned short* WT;
        int K;
        if (layer == 0)      { W = W1; WT = WT1; K = 64; }
        else if (layer == 1) { W = W2; WT = WT2; K = 128; }
        else                 { W = W3; WT = WT3; K = 128; }
        int n = nt * 64 + (t & 63);
        for (int kg = (int)(t >> 6); kg < K / 8; kg += 4) {
            bf16x8 v;
#pragma unroll
            for (int e = 0; e < 8; ++e) v[e] = (short)f2bf(W[(size_t)(kg * 8 + e) * 640 + n]);
            *(bf16x8*)&WT[(size_t)n * K + kg * 8] = v;
        }
    } else {
        int gt = (blk - 30) * 256 + t;                 // 524288 threads, 4 items each
        const int4* p = (const int4*)(bonds + (size_t)gt * 20);
        int4 q0 = p[0], q1 = p[1], q2 = p[2], q3 = p[3], q4 = p[4];
        int v[20] = {q0.x, q0.y, q0.z, q0.w, q1.x, q1.y, q1.z, q1.w,
                     q2.x, q2.y, q2.z, q2.w, q3.x, q3.y, q3.z, q3.w,
                     q4.x, q4.y, q4.z, q4.w};
        unsigned m = 0;
#pragma unroll
        for (int k = 0; k < 4; ++k)
#pragma unroll
            for (int r = 0; r < 5; ++r)
                m |= (v[k * 5 + r] == 1) ? (1u << (k * 8 + r)) : 0u;
        *(unsigned*)&maskp[(size_t)gt * 4] = m;
    }
}

// =======================================================================================
// gemm_h: h = A(8192 x K) @ W(K x 640) + bias, MFMA bf16 (fp32 accum).
// MODE 0: A = fp32 Af32 (layer 1). MODE 1: A = final bf16 Ab written by k_agg (plain load).
// Emits src/dst partial dots (2 halves) and hTf fragment-native:
//   hTf[((b*5 + r)*32 + joct)*1024 + c*8 + e]   (joct = j/8, e = j%8)
// grid (10 n-tiles of 64, 128 m-tiles of 64), 256 threads = 4 waves.
// =======================================================================================
template <int K, int MODE>
__global__ __launch_bounds__(256) void k_gemm_h(const float* __restrict__ Af32,
                                                const unsigned short* __restrict__ Ab,
                                                const unsigned short* __restrict__ WTg,
                                                const float* __restrict__ bias,
                                                const float* __restrict__ avec,
                                                float* __restrict__ srcp,
                                                float* __restrict__ dstp,
                                                unsigned short* __restrict__ hTf) {
    const int t = threadIdx.x;
    const int n0 = blockIdx.x * 64, m0 = blockIdx.y * 64;
    const int w = t >> 6, lane = t & 63;
    const int colg = lane & 15, rquad = lane >> 4;
    const int m = m0 + w * 16 + colg;        // A row this lane reads
    const int koff = rquad * 8;

    f32x4 acc[4] = {};
#pragma unroll
    for (int kk = 0; kk < K; kk += 32) {
        bf16x8 af;
        size_t off = (size_t)m * K + kk + koff;
        if (MODE == 1) {
            af = *(const bf16x8*)&Ab[off];
        } else {
            float4 q0 = *(const float4*)&Af32[off];
            float4 q1 = *(const float4*)&Af32[off + 4];
            af[0] = (short)f2bf(q0.x); af[1] = (short)f2bf(q0.y);
            af[2] = (short)f2bf(q0.z); af[3] = (short)f2bf(q0.w);
            af[4] = (short)f2bf(q1.x); af[5] = (short)f2bf(q1.y);
            af[6] = (short)f2bf(q1.z); af[7] = (short)f2bf(q1.w);
        }
#pragma unroll
        for (int ct = 0; ct < 4; ++ct) {
            bf16x8 bfv = *(const bf16x8*)&WTg[(size_t)(n0 + ct * 16 + colg) * K + kk + koff];
            acc[ct] = __builtin_amdgcn_mfma_f32_16x16x32_bf16(af, bfv, acc[ct], 0, 0, 0);
        }
    }

    // ---- epilogue: bias, src/dst partial dots (shfl-reduce over colg), hTf stores ----
    const int r = n0 >> 7, chalf = n0 & 127;
    const int b = m0 >> 8, jb = m0 & 255;
    float val[4][4];
    float ssum[4] = {0.f, 0.f, 0.f, 0.f}, dsum[4] = {0.f, 0.f, 0.f, 0.f};
#pragma unroll
    for (int ct = 0; ct < 4; ++ct) {
        int cg = chalf + ct * 16 + colg;
        float bv = bias[n0 + ct * 16 + colg];
        float asr = avec[r * 256 + cg];
        float ads = avec[r * 256 + 128 + cg];
#pragma unroll
        for (int reg = 0; reg < 4; ++reg) {
            float v = acc[ct][reg] + bv;
            val[ct][reg] = v;
            ssum[reg] += v * asr;
            dsum[reg] += v * ads;
        }
    }
#pragma unroll
    for (int mk = 1; mk < 16; mk <<= 1)
#pragma unroll
        for (int reg = 0; reg < 4; ++reg) {
            ssum[reg] += __shfl_xor(ssum[reg], mk);
            dsum[reg] += __shfl_xor(dsum[reg], mk);
        }
    if (colg == 0) {
        int half = (n0 >> 6) & 1;
#pragma unroll
        for (int reg = 0; reg < 4; ++reg) {
            int row = m0 + w * 16 + rquad * 4 + reg;
            srcp[half * 40960 + row * 5 + r] = ssum[reg];
            dstp[half * 40960 + row * 5 + r] = dsum[reg];
        }
    }
    // hTf direct stores: reg-quad = 4 consecutive j (8 B contiguous)
    {
        const int joct = (jb >> 3) + w * 2 + (rquad >> 1);
        const size_t tile = (size_t)((b * 5 + r) * 32 + joct) * 1024;
        const int sub = (rquad & 1) * 4;
#pragma unroll
        for (int ct = 0; ct < 4; ++ct) {
            int c = chalf + ct * 16 + colg;
            uint2 pk;
            pk.x = (unsigned)f2bf(val[ct][0]) | ((unsigned)f2bf(val[ct][1]) << 16);
            pk.y = (unsigned)f2bf(val[ct][2]) | ((unsigned)f2bf(val[ct][3]) << 16);
            *(uint2*)&hTf[tile + (size_t)c * 8 + sub] = pk;
        }
    }
}

// =======================================================================================
// k_agg: grid (16 i-tiles of 16, 32 b) = 512 blocks, 512 threads = 8 waves.
// Full j-range (256) per block: computes the complete softmax row sum Z, so it writes the
// FINAL normalized output directly:
//   FINAL=0: Ab[row][c] = bf16(lrelu(agg/Z))  (layers 1-2 -> next gemm A operand)
//   FINAL=1: per-block pooled partials over its 16 rows:
//            poolS/poolM[(b*16+itile)*128 + c]  (h3 never materialized)
// LDS: Ps 40 KB + Ds2l 5 KB + misc ~= 46 KB -> 2 blocks/CU (grid exactly 2/CU).
// =======================================================================================
template <int FINAL>
__global__ __launch_bounds__(512, 4) void k_agg(const unsigned short* __restrict__ hTf,
                                                const float* __restrict__ srcp,
                                                const float* __restrict__ dstp,
                                                const unsigned char* __restrict__ maskp,
                                                unsigned short* __restrict__ Ab,
                                                float* __restrict__ poolS,
                                                float* __restrict__ poolM) {
    __shared__ __align__(16) unsigned short Ps[20480];   // 16 i x 1280 k bf16 = 40 KB
    __shared__ __align__(16) float Ds2l[1280];
    __shared__ float Ss[80], Zw[128], Zrow[16];
    const int t = threadIdx.x;
    const int itile = blockIdx.x, b = blockIdx.y;
    const int ib = b * 256 + itile * 16;
    const int w = t >> 6, lane = t & 63;
    const int colg = lane & 15, rquad = lane >> 4;
    const int c = w * 16 + colg;                          // output column this wave owns
    const size_t bbase = (size_t)(b * 5) * 32 * 1024;

    if (t < 80) Ss[t] = srcp[(size_t)ib * 5 + t] + srcp[40960 + (size_t)ib * 5 + t];
    for (int idx = t; idx < 1280; idx += 512) {
        int jl = idx & 255, rr = idx >> 8;
        size_t o = (size_t)(b * 256 + jl) * 5 + rr;
        Ds2l[rr * 256 + jl] = dstp[o] + dstp[40960 + o];
    }
    // B prefetch for MFMA steps 0..3 (independent of Ps; streams under P-gen VALU)
    bf16x8 pre[4];
#pragma unroll
    for (int s = 0; s < 4; ++s)
        pre[s] = *(const bf16x8*)&hTf[bbase + (size_t)(s * 4 + rquad) * 1024 + (size_t)c * 8];
    __syncthreads();

    // P generation: 2560 chunks of 8; thread t -> chunks it*512+t (i = t&15 fixed)
    {
        const int i = t & 15;
        const int kq = (t >> 4) & 3;
        float esum = 0.f;
#pragma unroll
        for (int it = 0; it < 5; ++it) {
            int p = it * 512 + t;
            int s = p >> 6;                           // s in [0,40)
            int k0 = s * 32 + kq * 8;                 // k0 in [0,1280)
            int rr = k0 >> 8, j0 = k0 & 255;
            uint2 mk8 = *(const uint2*)&maskp[((size_t)(ib + i) << 8) + j0];
            float sv = Ss[i * 5 + rr];
            float4 d0 = *(const float4*)&Ds2l[rr * 256 + j0];
            float4 d1 = *(const float4*)&Ds2l[rr * 256 + j0 + 4];
            float dv[8] = {d0.x, d0.y, d0.z, d0.w, d1.x, d1.y, d1.z, d1.w};
            bf16x8 pv;
#pragma unroll
            for (int e = 0; e < 8; ++e) {
                unsigned mb = ((e < 4 ? (mk8.x >> (8 * e)) : (mk8.y >> (8 * (e - 4)))) >> rr) & 1u;
                float vv = lrelu(sv + dv[e]);
                float ev = mb ? __expf(vv) : 0.f;
                unsigned short q = f2bf(ev);
                pv[e] = (short)q;
                esum += __uint_as_float((unsigned)q << 16);
            }
            *(bf16x8*)&Ps[p * 8] = pv;
        }
        // lanes {i, i+16, i+32, i+48} share i -> butterfly over bits 4,5
        esum += __shfl_xor(esum, 16);
        esum += __shfl_xor(esum, 32);
        if (lane < 16) Zw[w * 16 + (lane & 15)] = esum;
    }
    __syncthreads();
    if (t < 16) {
        float z = 0.f;
#pragma unroll
        for (int ww = 0; ww < 8; ++ww) z += Zw[ww * 16 + t];
        Zrow[t] = 1.f / z;                            // store reciprocal once
    }

    // MFMA: wave w -> 16 columns; 40 steps over (r, j-window); 2 accumulator chains
    f32x4 acc0 = {}, acc1 = {};
#pragma unroll
    for (int s = 0; s < 8; ++s) {                     // peeled: static pre[] indexing
        bf16x8 af = *(const bf16x8*)&Ps[(s * 64 + lane) * 8];
        bf16x8 bfv;
        if (s < 4) bfv = pre[s];
        else bfv = *(const bf16x8*)&hTf[bbase + (size_t)((s & 7) * 4 + rquad) * 1024 + (size_t)c * 8];
        if (s & 1) acc1 = __builtin_amdgcn_mfma_f32_16x16x32_bf16(af, bfv, acc1, 0, 0, 0);
        else       acc0 = __builtin_amdgcn_mfma_f32_16x16x32_bf16(af, bfv, acc0, 0, 0, 0);
    }
#pragma unroll 8
    for (int s = 8; s < 40; ++s) {
        bf16x8 af = *(const bf16x8*)&Ps[(s * 64 + lane) * 8];
        bf16x8 bfv = *(const bf16x8*)&hTf[bbase +
            (size_t)((s >> 3) * 32 + (s & 7) * 4 + rquad) * 1024 + (size_t)c * 8];
        if (s & 1) acc1 = __builtin_amdgcn_mfma_f32_16x16x32_bf16(af, bfv, acc1, 0, 0, 0);
        else       acc0 = __builtin_amdgcn_mfma_f32_16x16x32_bf16(af, bfv, acc0, 0, 0, 0);
    }
    __syncthreads();                                  // Zrow visible to all
    const int irow = ib + rquad * 4;
    if (FINAL) {
        // pool this block's 16 rows per column: 4 in-lane regs + rquad butterfly
        float ps = 0.f, pm = -3.4e38f;
#pragma unroll
        for (int reg = 0; reg < 4; ++reg) {
            float v = (acc0[reg] + acc1[reg]) * Zrow[rquad * 4 + reg];
            ps += v;
            pm = fmaxf(pm, v);
        }
        ps += __shfl_xor(ps, 16);
        ps += __shfl_xor(ps, 32);
        pm = fmaxf(pm, __shfl_xor(pm, 16));
        pm = fmaxf(pm, __shfl_xor(pm, 32));
        if (rquad == 0) {
            poolS[(size_t)(b * 16 + itile) * 128 + c] = ps;
            poolM[(size_t)(b * 16 + itile) * 128 + c] = pm;
        }
    } else {
#pragma unroll
        for (int reg = 0; reg < 4; ++reg) {
            float v = (acc0[reg] + acc1[reg]) * Zrow[rquad * 4 + reg];
            Ab[(size_t)(irow + reg) * 128 + c] = f2bf(lrelu(v));
        }
    }
}

// =======================================================================================
// k_mlp1: z1 partials. grid (5 k-chunks, 32 b) = 160 blocks, 256 threads.
// Thread t owns output o=t; k-chunk kg covers z[kg*256 .. kg*256+256):
//   kg<4 -> x slice; kg==4 -> [mean(128) | max(128)] built from the 16 pool partials.
// Coalesced native-layout We1 reads (stride-256 rows, contiguous over t).
// =======================================================================================
__global__ __launch_bounds__(256) void k_mlp1(const float* __restrict__ x,
                                              const float* __restrict__ poolS,
                                              const float* __restrict__ poolM,
                                              const float* __restrict__ We1,
                                              float* __restrict__ z1p) {
    const int kg = blockIdx.x, b = blockIdx.y;
    const int t = threadIdx.x;
    __shared__ float zs[256];
    if (kg < 4) {
        zs[t] = x[(size_t)b * 1024 + kg * 256 + t];
    } else if (t < 128) {
        float s = 0.f;
#pragma unroll
        for (int it = 0; it < 16; ++it) s += poolS[(size_t)(b * 16 + it) * 128 + t];
        zs[t] = s * (1.f / 256.f);
    } else {
        int f = t - 128;
        float mx = -3.4e38f;
#pragma unroll
        for (int it = 0; it < 16; ++it) mx = fmaxf(mx, poolM[(size_t)(b * 16 + it) * 128 + f]);
        zs[t] = mx;
    }
    __syncthreads();
    float s = 0.f;
#pragma unroll 8
    for (int k = 0; k < 256; ++k) s += zs[k] * We1[(size_t)(kg * 256 + k) * 256 + t];
    z1p[(size_t)(b * 5 + kg) * 256 + t] = s;
}

// =======================================================================================
// k_mlp2: combine z1 partials + bias + lrelu; mlp2 (k-split 8x32 + LDS reduce); mlp3.
// grid (32 b), 256 threads.
// =======================================================================================
__global__ __launch_bounds__(256) void k_mlp2(const float* __restrict__ z1p,
                                              const float* __restrict__ be1,
                                              const float* __restrict__ We2,
                                              const float* __restrict__ be2,
                                              const float* __restrict__ We3,
                                              const float* __restrict__ be3,
                                              float* __restrict__ out) {
    const int b = blockIdx.x, t = threadIdx.x;
    __shared__ float z1s[256];
    __shared__ float s2p[8][32];
    __shared__ float z2s[32];
    {
        float s = be1[t];
#pragma unroll
        for (int kg = 0; kg < 5; ++kg) s += z1p[(size_t)(b * 5 + kg) * 256 + t];
        z1s[t] = lrelu(s);
    }
    __syncthreads();
    {
        int o = t & 31, g = t >> 5;
        float p = 0.f;
#pragma unroll
        for (int k = 0; k < 32; ++k) p += z1s[g * 32 + k] * We2[(g * 32 + k) * 32 + o];
        s2p[g][o] = p;
    }
    __syncthreads();
    if (t < 32) {
        float s2 = be2[t];
#pragma unroll
        for (int g = 0; g < 8; ++g) s2 += s2p[g][t];
        z2s[t] = lrelu(s2);
    }
    __syncthreads();
    if (t == 0) {
        float s3 = be3[0];
#pragma unroll
        for (int k = 0; k < 32; ++k) s3 += z2s[k] * We3[k];
        out[b] = s3;
    }
}

// ---------------- workspace layout ----------------
constexpr size_t O_MASK  = 0;                           // 2,097,152
constexpr size_t O_SRCP  = 2097152;                     // 2 x 40960 floats
constexpr size_t O_DSTP  = O_SRCP + 2ull * 40960 * 4;
constexpr size_t O_AB    = O_DSTP + 2ull * 40960 * 4;   // 8192 x 128 bf16 = 2 MB
constexpr size_t O_HT    = O_AB + 2097152;              // 10.5 MB
constexpr size_t O_WT1   = O_HT + 5242880ull * 2;
constexpr size_t O_WT2   = O_WT1 + 640ull * 64 * 2;
constexpr size_t O_WT3   = O_WT2 + 640ull * 128 * 2;
constexpr size_t O_POOLS = O_WT3 + 640ull * 128 * 2;    // 32 x 16 x 128 fp32 = 256 KB
constexpr size_t O_POOLM = O_POOLS + 32ull * 16 * 128 * 4;
constexpr size_t O_Z1P   = O_POOLM + 32ull * 16 * 128 * 4; // 32 x 5 x 256 fp32 = 160 KB

extern "C" void kernel_launch(void* const* d_in, const int* in_sizes, int n_in,
                              void* d_out, int out_size, void* d_ws, size_t ws_size,
                              hipStream_t stream) {
    const float* x       = (const float*)d_in[0];
    const float* y_atoms = (const float*)d_in[1];
    const int*   y_bonds = (const int*)d_in[2];
    const float* W1 = (const float*)d_in[3];
    const float* b1 = (const float*)d_in[4];
    const float* a1 = (const float*)d_in[5];
    const float* W2 = (const float*)d_in[6];
    const float* b2 = (const float*)d_in[7];
    const float* a2 = (const float*)d_in[8];
    const float* W3 = (const float*)d_in[9];
    const float* b3 = (const float*)d_in[10];
    const float* a3 = (const float*)d_in[11];
    const float* We1 = (const float*)d_in[12];
    const float* be1 = (const float*)d_in[13];
    const float* We2 = (const float*)d_in[14];
    const float* be2 = (const float*)d_in[15];
    const float* We3 = (const float*)d_in[16];
    const float* be3 = (const float*)d_in[17];
    float* out = (float*)d_out;

    char* ws = (char*)d_ws;
    unsigned char* maskp = (unsigned char*)(ws + O_MASK);
    float* srcp = (float*)(ws + O_SRCP);
    float* dstp = (float*)(ws + O_DSTP);
    unsigned short* Ab = (unsigned short*)(ws + O_AB);
    unsigned short* hTf = (unsigned short*)(ws + O_HT);
    unsigned short* WT1 = (unsigned short*)(ws + O_WT1);
    unsigned short* WT2 = (unsigned short*)(ws + O_WT2);
    unsigned short* WT3 = (unsigned short*)(ws + O_WT3);
    float* poolS = (float*)(ws + O_POOLS);
    float* poolM = (float*)(ws + O_POOLM);
    float* z1p   = (float*)(ws + O_Z1P);

    dim3 blk(256);

    k_prep<<<2078, blk, 0, stream>>>(W1, W2, W3, y_bonds, WT1, WT2, WT3, maskp);

    // layer 1
    k_gemm_h<64, 0><<<dim3(10, 128), blk, 0, stream>>>(
        y_atoms, nullptr, WT1, b1, a1, srcp, dstp, hTf);
    k_agg<0><<<dim3(16, 32), dim3(512), 0, stream>>>(hTf, srcp, dstp, maskp, Ab, nullptr, nullptr);

    // layer 2
    k_gemm_h<128, 1><<<dim3(10, 128), blk, 0, stream>>>(
        nullptr, Ab, WT2, b2, a2, srcp, dstp, hTf);
    k_agg<0><<<dim3(16, 32), dim3(512), 0, stream>>>(hTf, srcp, dstp, maskp, Ab, nullptr, nullptr);

    // layer 3
    k_gemm_h<128, 1><<<dim3(10, 128), blk, 0, stream>>>(
        nullptr, Ab, WT3, b3, a3, srcp, dstp, hTf);
    k_agg<1><<<dim3(16, 32), dim3(512), 0, stream>>>(hTf, srcp, dstp, maskp, nullptr, poolS, poolM);

    // distributed MLP head
    k_mlp1<<<dim3(5, 32), blk, 0, stream>>>(x, poolS, poolM, We1, z1p);
    k_mlp2<<<32, blk, 0, stream>>>(z1p, be1, We2, be2, We3, be3, out);
}

// Round 4
// 202.113 us; speedup vs baseline: 1.3107x; 1.0964x over previous
//
#include <hip/hip_runtime.h>
#include <cstddef>

#define BB 32
#define NN 256
#define RR 5

typedef __attribute__((ext_vector_type(8))) short bf16x8;
typedef __attribute__((ext_vector_type(4))) float f32x4;

__device__ __forceinline__ float lrelu(float x) { return x >= 0.f ? x : 0.2f * x; }
// RNE float -> bf16
__device__ __forceinline__ unsigned short f2bf(float x) {
    unsigned u = __float_as_uint(x);
    u += 0x7FFFu + ((u >> 16) & 1u);
    return (unsigned short)(u >> 16);
}
__device__ __forceinline__ float bf2f(unsigned short u) {
    return __uint_as_float((unsigned)u << 16);
}

// =======================================================================================
// k_prep: blocks 0..29: W (K x 640 fp32) -> WT (640 x K bf16).
// blocks 30..2077: pack y_bonds -> maskp, 4 items/thread via int4 loads + uint store.
// =======================================================================================
__global__ __launch_bounds__(256) void k_prep(const float* __restrict__ W1,
                                              const float* __restrict__ W2,
                                              const float* __restrict__ W3,
                                              const int* __restrict__ bonds,
                                              unsigned short* __restrict__ WT1,
                                              unsigned short* __restrict__ WT2,
                                              unsigned short* __restrict__ WT3,
                                              unsigned char* __restrict__ maskp) {
    int blk = blockIdx.x;
    int t = threadIdx.x;
    if (blk < 30) {
        int layer = blk / 10, nt = blk % 10;
        const float* W;
        unsigned short* WT;
        int K;
        if (layer == 0)      { W = W1; WT = WT1; K = 64; }
        else if (layer == 1) { W = W2; WT = WT2; K = 128; }
        else                 { W = W3; WT = WT3; K = 128; }
        int n = nt * 64 + (t & 63);
        for (int kg = (int)(t >> 6); kg < K / 8; kg += 4) {
            bf16x8 v;
#pragma unroll
            for (int e = 0; e < 8; ++e) v[e] = (short)f2bf(W[(size_t)(kg * 8 + e) * 640 + n]);
            *(bf16x8*)&WT[(size_t)n * K + kg * 8] = v;
        }
    } else {
        int gt = (blk - 30) * 256 + t;                 // 524288 threads, 4 items each
        const int4* p = (const int4*)(bonds + (size_t)gt * 20);
        int4 q0 = p[0], q1 = p[1], q2 = p[2], q3 = p[3], q4 = p[4];
        int v[20] = {q0.x, q0.y, q0.z, q0.w, q1.x, q1.y, q1.z, q1.w,
                     q2.x, q2.y, q2.z, q2.w, q3.x, q3.y, q3.z, q3.w,
                     q4.x, q4.y, q4.z, q4.w};
        unsigned m = 0;
#pragma unroll
        for (int k = 0; k < 4; ++k)
#pragma unroll
            for (int r = 0; r < 5; ++r)
                m |= (v[k * 5 + r] == 1) ? (1u << (k * 8 + r)) : 0u;
        *(unsigned*)&maskp[(size_t)gt * 4] = m;
    }
}

// =======================================================================================
// gemm_h: h = A(8192 x K) @ W(K x 640) + bias, MFMA bf16 (fp32 accum).
// MODE 0: A = fp32 Af32 (layer 1). MODE 1: A = final bf16 Ab written by k_agg (plain load).
// Emits src/dst partial dots (2 halves) and hTf fragment-native:
//   hTf[((b*5 + r)*32 + joct)*1024 + c*8 + e]   (joct = j/8, e = j%8)
// 1-D grid of 1280, XCD-affinity swizzle: XCD(mt)=mt/16=b/4 so that (a) the 10 n-tile
// blocks sharing one m-tile's A rows co-reside on one XCD L2, (b) hTf writes for batch b
// land on the same XCD that k_agg reads them from. 256 threads = 4 waves.
// =======================================================================================
template <int K, int MODE>
__global__ __launch_bounds__(256) void k_gemm_h(const float* __restrict__ Af32,
                                                const unsigned short* __restrict__ Ab,
                                                const unsigned short* __restrict__ WTg,
                                                const float* __restrict__ bias,
                                                const float* __restrict__ avec,
                                                float* __restrict__ srcp,
                                                float* __restrict__ dstp,
                                                unsigned short* __restrict__ hTf) {
    const int t = threadIdx.x;
    // bijective swizzle: l = nt*128 + (mt&15)*8 + (mt>>4)
    const int l = blockIdx.x;
    const int mt = (l & 7) * 16 + ((l >> 3) & 15);   // [0,128)
    const int nt = l >> 7;                            // [0,10)
    const int n0 = nt * 64, m0 = mt * 64;
    const int w = t >> 6, lane = t & 63;
    const int colg = lane & 15, rquad = lane >> 4;
    const int m = m0 + w * 16 + colg;        // A row this lane reads
    const int koff = rquad * 8;

    f32x4 acc[4] = {};
#pragma unroll
    for (int kk = 0; kk < K; kk += 32) {
        bf16x8 af;
        size_t off = (size_t)m * K + kk + koff;
        if (MODE == 1) {
            af = *(const bf16x8*)&Ab[off];
        } else {
            float4 q0 = *(const float4*)&Af32[off];
            float4 q1 = *(const float4*)&Af32[off + 4];
            af[0] = (short)f2bf(q0.x); af[1] = (short)f2bf(q0.y);
            af[2] = (short)f2bf(q0.z); af[3] = (short)f2bf(q0.w);
            af[4] = (short)f2bf(q1.x); af[5] = (short)f2bf(q1.y);
            af[6] = (short)f2bf(q1.z); af[7] = (short)f2bf(q1.w);
        }
#pragma unroll
        for (int ct = 0; ct < 4; ++ct) {
            bf16x8 bfv = *(const bf16x8*)&WTg[(size_t)(n0 + ct * 16 + colg) * K + kk + koff];
            acc[ct] = __builtin_amdgcn_mfma_f32_16x16x32_bf16(af, bfv, acc[ct], 0, 0, 0);
        }
    }

    // ---- epilogue: bias, src/dst partial dots (shfl-reduce over colg), hTf stores ----
    const int r = n0 >> 7, chalf = n0 & 127;
    const int b = m0 >> 8, jb = m0 & 255;
    float val[4][4];
    float ssum[4] = {0.f, 0.f, 0.f, 0.f}, dsum[4] = {0.f, 0.f, 0.f, 0.f};
#pragma unroll
    for (int ct = 0; ct < 4; ++ct) {
        int cg = chalf + ct * 16 + colg;
        float bv = bias[n0 + ct * 16 + colg];
        float asr = avec[r * 256 + cg];
        float ads = avec[r * 256 + 128 + cg];
#pragma unroll
        for (int reg = 0; reg < 4; ++reg) {
            float v = acc[ct][reg] + bv;
            val[ct][reg] = v;
            ssum[reg] += v * asr;
            dsum[reg] += v * ads;
        }
    }
#pragma unroll
    for (int mk = 1; mk < 16; mk <<= 1)
#pragma unroll
        for (int reg = 0; reg < 4; ++reg) {
            ssum[reg] += __shfl_xor(ssum[reg], mk);
            dsum[reg] += __shfl_xor(dsum[reg], mk);
        }
    if (colg == 0) {
        int half = (n0 >> 6) & 1;
#pragma unroll
        for (int reg = 0; reg < 4; ++reg) {
            int row = m0 + w * 16 + rquad * 4 + reg;
            srcp[half * 40960 + row * 5 + r] = ssum[reg];
            dstp[half * 40960 + row * 5 + r] = dsum[reg];
        }
    }
    // hTf direct stores: reg-quad = 4 consecutive j (8 B contiguous)
    {
        const int joct = (jb >> 3) + w * 2 + (rquad >> 1);
        const size_t tile = (size_t)((b * 5 + r) * 32 + joct) * 1024;
        const int sub = (rquad & 1) * 4;
#pragma unroll
        for (int ct = 0; ct < 4; ++ct) {
            int c = chalf + ct * 16 + colg;
            uint2 pk;
            pk.x = (unsigned)f2bf(val[ct][0]) | ((unsigned)f2bf(val[ct][1]) << 16);
            pk.y = (unsigned)f2bf(val[ct][2]) | ((unsigned)f2bf(val[ct][3]) << 16);
            *(uint2*)&hTf[tile + (size_t)c * 8 + sub] = pk;
        }
    }
}

// =======================================================================================
// k_agg: 1-D grid of 512, 512 threads = 8 waves. XCD-affinity swizzle: the 16 i-tile
// blocks of batch b all stream the SAME 327 KB hTf slice; mapping them to one XCD
// (XCD(b)=b/4, 64 blocks/XCD, all co-resident at 2 blocks/CU) turns the 16x re-read
// into per-XCD L2 hits instead of L3/HBM round-trips.
// Full j-range (256) per block: computes the complete softmax row sum Z, writes the
// FINAL normalized output directly:
//   FINAL=0: Ab[row][c] = bf16(lrelu(agg/Z))  (layers 1-2 -> next gemm A operand)
//   FINAL=1: per-block pooled partials over its 16 rows:
//            poolS/poolM[(b*16+itile)*128 + c]  (h3 never materialized)
// LDS: Ps 40 KB + Ds2l 5 KB + misc ~= 46 KB.
// =======================================================================================
template <int FINAL>
__global__ __launch_bounds__(512, 4) void k_agg(const unsigned short* __restrict__ hTf,
                                                const float* __restrict__ srcp,
                                                const float* __restrict__ dstp,
                                                const unsigned char* __restrict__ maskp,
                                                unsigned short* __restrict__ Ab,
                                                float* __restrict__ poolS,
                                                float* __restrict__ poolM) {
    __shared__ __align__(16) unsigned short Ps[20480];   // 16 i x 1280 k bf16 = 40 KB
    __shared__ __align__(16) float Ds2l[1280];
    __shared__ float Ss[80], Zw[128], Zrow[16];
    const int t = threadIdx.x;
    // bijective swizzle: l = itile*32 + (b&3)*8 + (b>>2)
    const int l = blockIdx.x;
    const int b = (l & 7) * 4 + ((l >> 3) & 3);       // [0,32), XCD(b)=b/4
    const int itile = l >> 5;                          // [0,16)
    const int ib = b * 256 + itile * 16;
    const int w = t >> 6, lane = t & 63;
    const int colg = lane & 15, rquad = lane >> 4;
    const int c = w * 16 + colg;                          // output column this wave owns
    const size_t bbase = (size_t)(b * 5) * 32 * 1024;

    if (t < 80) Ss[t] = srcp[(size_t)ib * 5 + t] + srcp[40960 + (size_t)ib * 5 + t];
    for (int idx = t; idx < 1280; idx += 512) {
        int jl = idx & 255, rr = idx >> 8;
        size_t o = (size_t)(b * 256 + jl) * 5 + rr;
        Ds2l[rr * 256 + jl] = dstp[o] + dstp[40960 + o];
    }
    // B prefetch for MFMA steps 0..3 (independent of Ps; streams under P-gen VALU)
    bf16x8 pre[4];
#pragma unroll
    for (int s = 0; s < 4; ++s)
        pre[s] = *(const bf16x8*)&hTf[bbase + (size_t)(s * 4 + rquad) * 1024 + (size_t)c * 8];
    __syncthreads();

    // P generation: 2560 chunks of 8; thread t -> chunks it*512+t (i = t&15 fixed)
    {
        const int i = t & 15;
        const int kq = (t >> 4) & 3;
        float esum = 0.f;
#pragma unroll
        for (int it = 0; it < 5; ++it) {
            int p = it * 512 + t;
            int s = p >> 6;                           // s in [0,40)
            int k0 = s * 32 + kq * 8;                 // k0 in [0,1280)
            int rr = k0 >> 8, j0 = k0 & 255;
            uint2 mk8 = *(const uint2*)&maskp[((size_t)(ib + i) << 8) + j0];
            float sv = Ss[i * 5 + rr];
            float4 d0 = *(const float4*)&Ds2l[rr * 256 + j0];
            float4 d1 = *(const float4*)&Ds2l[rr * 256 + j0 + 4];
            float dv[8] = {d0.x, d0.y, d0.z, d0.w, d1.x, d1.y, d1.z, d1.w};
            bf16x8 pv;
#pragma unroll
            for (int e = 0; e < 8; ++e) {
                unsigned mb = ((e < 4 ? (mk8.x >> (8 * e)) : (mk8.y >> (8 * (e - 4)))) >> rr) & 1u;
                float vv = lrelu(sv + dv[e]);
                float ev = mb ? __expf(vv) : 0.f;
                unsigned short q = f2bf(ev);
                pv[e] = (short)q;
                esum += __uint_as_float((unsigned)q << 16);
            }
            *(bf16x8*)&Ps[p * 8] = pv;
        }
        // lanes {i, i+16, i+32, i+48} share i -> butterfly over bits 4,5
        esum += __shfl_xor(esum, 16);
        esum += __shfl_xor(esum, 32);
        if (lane < 16) Zw[w * 16 + (lane & 15)] = esum;
    }
    __syncthreads();
    if (t < 16) {
        float z = 0.f;
#pragma unroll
        for (int ww = 0; ww < 8; ++ww) z += Zw[ww * 16 + t];
        Zrow[t] = 1.f / z;                            // store reciprocal once
    }

    // MFMA: wave w -> 16 columns; 40 steps over (r, j-window); 2 accumulator chains
    f32x4 acc0 = {}, acc1 = {};
#pragma unroll
    for (int s = 0; s < 8; ++s) {                     // peeled: static pre[] indexing
        bf16x8 af = *(const bf16x8*)&Ps[(s * 64 + lane) * 8];
        bf16x8 bfv;
        if (s < 4) bfv = pre[s];
        else bfv = *(const bf16x8*)&hTf[bbase + (size_t)((s & 7) * 4 + rquad) * 1024 + (size_t)c * 8];
        if (s & 1) acc1 = __builtin_amdgcn_mfma_f32_16x16x32_bf16(af, bfv, acc1, 0, 0, 0);
        else       acc0 = __builtin_amdgcn_mfma_f32_16x16x32_bf16(af, bfv, acc0, 0, 0, 0);
    }
#pragma unroll 8
    for (int s = 8; s < 40; ++s) {
        bf16x8 af = *(const bf16x8*)&Ps[(s * 64 + lane) * 8];
        bf16x8 bfv = *(const bf16x8*)&hTf[bbase +
            (size_t)((s >> 3) * 32 + (s & 7) * 4 + rquad) * 1024 + (size_t)c * 8];
        if (s & 1) acc1 = __builtin_amdgcn_mfma_f32_16x16x32_bf16(af, bfv, acc1, 0, 0, 0);
        else       acc0 = __builtin_amdgcn_mfma_f32_16x16x32_bf16(af, bfv, acc0, 0, 0, 0);
    }
    __syncthreads();                                  // Zrow visible to all
    const int irow = ib + rquad * 4;
    if (FINAL) {
        // pool this block's 16 rows per column: 4 in-lane regs + rquad butterfly
        float ps = 0.f, pm = -3.4e38f;
#pragma unroll
        for (int reg = 0; reg < 4; ++reg) {
            float v = (acc0[reg] + acc1[reg]) * Zrow[rquad * 4 + reg];
            ps += v;
            pm = fmaxf(pm, v);
        }
        ps += __shfl_xor(ps, 16);
        ps += __shfl_xor(ps, 32);
        pm = fmaxf(pm, __shfl_xor(pm, 16));
        pm = fmaxf(pm, __shfl_xor(pm, 32));
        if (rquad == 0) {
            poolS[(size_t)(b * 16 + itile) * 128 + c] = ps;
            poolM[(size_t)(b * 16 + itile) * 128 + c] = pm;
        }
    } else {
#pragma unroll
        for (int reg = 0; reg < 4; ++reg) {
            float v = (acc0[reg] + acc1[reg]) * Zrow[rquad * 4 + reg];
            Ab[(size_t)(irow + reg) * 128 + c] = f2bf(lrelu(v));
        }
    }
}

// =======================================================================================
// k_mlp1: z1 partials. grid (5 k-chunks, 32 b) = 160 blocks, 256 threads.
// Thread t owns output o=t; k-chunk kg covers z[kg*256 .. kg*256+256):
//   kg<4 -> x slice; kg==4 -> [mean(128) | max(128)] built from the 16 pool partials.
// Coalesced native-layout We1 reads (stride-256 rows, contiguous over t).
// =======================================================================================
__global__ __launch_bounds__(256) void k_mlp1(const float* __restrict__ x,
                                              const float* __restrict__ poolS,
                                              const float* __restrict__ poolM,
                                              const float* __restrict__ We1,
                                              float* __restrict__ z1p) {
    const int kg = blockIdx.x, b = blockIdx.y;
    const int t = threadIdx.x;
    __shared__ float zs[256];
    if (kg < 4) {
        zs[t] = x[(size_t)b * 1024 + kg * 256 + t];
    } else if (t < 128) {
        float s = 0.f;
#pragma unroll
        for (int it = 0; it < 16; ++it) s += poolS[(size_t)(b * 16 + it) * 128 + t];
        zs[t] = s * (1.f / 256.f);
    } else {
        int f = t - 128;
        float mx = -3.4e38f;
#pragma unroll
        for (int it = 0; it < 16; ++it) mx = fmaxf(mx, poolM[(size_t)(b * 16 + it) * 128 + f]);
        zs[t] = mx;
    }
    __syncthreads();
    float s = 0.f;
#pragma unroll 8
    for (int k = 0; k < 256; ++k) s += zs[k] * We1[(size_t)(kg * 256 + k) * 256 + t];
    z1p[(size_t)(b * 5 + kg) * 256 + t] = s;
}

// =======================================================================================
// k_mlp2: combine z1 partials + bias + lrelu; mlp2 (k-split 8x32 + LDS reduce); mlp3.
// grid (32 b), 256 threads.
// =======================================================================================
__global__ __launch_bounds__(256) void k_mlp2(const float* __restrict__ z1p,
                                              const float* __restrict__ be1,
                                              const float* __restrict__ We2,
                                              const float* __restrict__ be2,
                                              const float* __restrict__ We3,
                                              const float* __restrict__ be3,
                                              float* __restrict__ out) {
    const int b = blockIdx.x, t = threadIdx.x;
    __shared__ float z1s[256];
    __shared__ float s2p[8][32];
    __shared__ float z2s[32];
    {
        float s = be1[t];
#pragma unroll
        for (int kg = 0; kg < 5; ++kg) s += z1p[(size_t)(b * 5 + kg) * 256 + t];
        z1s[t] = lrelu(s);
    }
    __syncthreads();
    {
        int o = t & 31, g = t >> 5;
        float p = 0.f;
#pragma unroll
        for (int k = 0; k < 32; ++k) p += z1s[g * 32 + k] * We2[(g * 32 + k) * 32 + o];
        s2p[g][o] = p;
    }
    __syncthreads();
    if (t < 32) {
        float s2 = be2[t];
#pragma unroll
        for (int g = 0; g < 8; ++g) s2 += s2p[g][t];
        z2s[t] = lrelu(s2);
    }
    __syncthreads();
    if (t == 0) {
        float s3 = be3[0];
#pragma unroll
        for (int k = 0; k < 32; ++k) s3 += z2s[k] * We3[k];
        out[b] = s3;
    }
}

// ---------------- workspace layout ----------------
constexpr size_t O_MASK  = 0;                           // 2,097,152
constexpr size_t O_SRCP  = 2097152;                     // 2 x 40960 floats
constexpr size_t O_DSTP  = O_SRCP + 2ull * 40960 * 4;
constexpr size_t O_AB    = O_DSTP + 2ull * 40960 * 4;   // 8192 x 128 bf16 = 2 MB
constexpr size_t O_HT    = O_AB + 2097152;              // 10.5 MB
constexpr size_t O_WT1   = O_HT + 5242880ull * 2;
constexpr size_t O_WT2   = O_WT1 + 640ull * 64 * 2;
constexpr size_t O_WT3   = O_WT2 + 640ull * 128 * 2;
constexpr size_t O_POOLS = O_WT3 + 640ull * 128 * 2;    // 32 x 16 x 128 fp32 = 256 KB
constexpr size_t O_POOLM = O_POOLS + 32ull * 16 * 128 * 4;
constexpr size_t O_Z1P   = O_POOLM + 32ull * 16 * 128 * 4; // 32 x 5 x 256 fp32 = 160 KB

extern "C" void kernel_launch(void* const* d_in, const int* in_sizes, int n_in,
                              void* d_out, int out_size, void* d_ws, size_t ws_size,
                              hipStream_t stream) {
    const float* x       = (const float*)d_in[0];
    const float* y_atoms = (const float*)d_in[1];
    const int*   y_bonds = (const int*)d_in[2];
    const float* W1 = (const float*)d_in[3];
    const float* b1 = (const float*)d_in[4];
    const float* a1 = (const float*)d_in[5];
    const float* W2 = (const float*)d_in[6];
    const float* b2 = (const float*)d_in[7];
    const float* a2 = (const float*)d_in[8];
    const float* W3 = (const float*)d_in[9];
    const float* b3 = (const float*)d_in[10];
    const float* a3 = (const float*)d_in[11];
    const float* We1 = (const float*)d_in[12];
    const float* be1 = (const float*)d_in[13];
    const float* We2 = (const float*)d_in[14];
    const float* be2 = (const float*)d_in[15];
    const float* We3 = (const float*)d_in[16];
    const float* be3 = (const float*)d_in[17];
    float* out = (float*)d_out;

    char* ws = (char*)d_ws;
    unsigned char* maskp = (unsigned char*)(ws + O_MASK);
    float* srcp = (float*)(ws + O_SRCP);
    float* dstp = (float*)(ws + O_DSTP);
    unsigned short* Ab = (unsigned short*)(ws + O_AB);
    unsigned short* hTf = (unsigned short*)(ws + O_HT);
    unsigned short* WT1 = (unsigned short*)(ws + O_WT1);
    unsigned short* WT2 = (unsigned short*)(ws + O_WT2);
    unsigned short* WT3 = (unsigned short*)(ws + O_WT3);
    float* poolS = (float*)(ws + O_POOLS);
    float* poolM = (float*)(ws + O_POOLM);
    float* z1p   = (float*)(ws + O_Z1P);

    dim3 blk(256);

    k_prep<<<2078, blk, 0, stream>>>(W1, W2, W3, y_bonds, WT1, WT2, WT3, maskp);

    // layer 1
    k_gemm_h<64, 0><<<1280, blk, 0, stream>>>(
        y_atoms, nullptr, WT1, b1, a1, srcp, dstp, hTf);
    k_agg<0><<<512, dim3(512), 0, stream>>>(hTf, srcp, dstp, maskp, Ab, nullptr, nullptr);

    // layer 2
    k_gemm_h<128, 1><<<1280, blk, 0, stream>>>(
        nullptr, Ab, WT2, b2, a2, srcp, dstp, hTf);
    k_agg<0><<<512, dim3(512), 0, stream>>>(hTf, srcp, dstp, maskp, Ab, nullptr, nullptr);

    // layer 3
    k_gemm_h<128, 1><<<1280, blk, 0, stream>>>(
        nullptr, Ab, WT3, b3, a3, srcp, dstp, hTf);
    k_agg<1><<<512, dim3(512), 0, stream>>>(hTf, srcp, dstp, maskp, nullptr, poolS, poolM);

    // distributed MLP head
    k_mlp1<<<dim3(5, 32), blk, 0, stream>>>(x, poolS, poolM, We1, z1p);
    k_mlp2<<<32, blk, 0, stream>>>(z1p, be1, We2, be2, We3, be3, out);
}